// Round 3
// baseline (1530.047 us; speedup 1.0000x reference)
//
#include <hip/hip_runtime.h>
#include <hip/hip_bf16.h>

// Flash attention fwd, causal + key-padding mask, bf16 MFMA, fp32 softmax.
// BH=256, T=1024, D=128, B=32 (mask batch = bh % 32). MASK_NUM kept finite so
// degenerate all-masked rows reproduce the reference's uniform softmax —
// including an extra pass over FUTURE tiles when a row's whole causal prefix
// is masked (reference then weights all 1024 keys uniformly).

typedef __attribute__((ext_vector_type(8))) __bf16 bf16x8;
typedef __attribute__((ext_vector_type(8))) short s16x8;
typedef __attribute__((ext_vector_type(4))) short s16x4;
typedef __attribute__((ext_vector_type(2))) short s16x2;
typedef __attribute__((ext_vector_type(4))) float f32x4;

#define T_SEQ   1024
#define D_HEAD  128
#define N_BATCH 32
#define QBLK    64
#define KVBLK   64
#define KPAD    136   // K lds row elems
#define VPAD    72    // Vt lds row elems
#define PPAD    72
#define MASK_NUM  (-4294967295.0f)   // -2^32 + 1 (rounds to -2^32 in fp32, same as jax)
#define SCALE     0.08838834764831845f

__device__ __forceinline__ short f2bf(float f) {
    union { float f; unsigned u; } v; v.f = f;
    unsigned r = v.u + 0x7fffu + ((v.u >> 16) & 1u);   // RNE
    return (short)(r >> 16);
}

__global__ __launch_bounds__(256) void fa_kernel(
    const float* __restrict__ Qg, const float* __restrict__ Kg,
    const float* __restrict__ Vg, const int* __restrict__ Mg,
    float* __restrict__ Og)
{
    __shared__ short Klds[KVBLK][KPAD];      // [key][d]
    __shared__ short Vlds[D_HEAD][VPAD];     // transposed: [d][key]
    __shared__ short Plds[4][16][PPAD];      // per-wave P re-layout buffer
    __shared__ int   degAny;

    const int qt   = blockIdx.x;             // q tile 0..15
    const int bh   = blockIdx.y;             // 0..255
    const int tid  = threadIdx.x;
    const int w    = tid >> 6;               // wave 0..3
    const int lane = tid & 63;
    const int l16  = lane & 15;
    const int lhi  = lane >> 4;              // 0..3

    const int    bidx  = bh & (N_BATCH - 1); // masks row = bh % 32 (jnp.tile)
    const size_t base  = (size_t)bh * T_SEQ * D_HEAD;
    const int    qrow0 = qt * QBLK + w * 16; // wave's first q row

    if (tid == 0) degAny = 0;

    // ---- Q fragments: A-layout, row = l16, k(d) = dk*32 + lhi*8 + j ----
    s16x8 qf[4];
    {
        const float* qp = Qg + base + (size_t)(qrow0 + l16) * D_HEAD + lhi * 8;
        #pragma unroll
        for (int dk = 0; dk < 4; ++dk) {
            float4 a = *(const float4*)(qp + dk * 32);
            float4 c = *(const float4*)(qp + dk * 32 + 4);
            s16x8 t;
            t[0] = f2bf(a.x); t[1] = f2bf(a.y); t[2] = f2bf(a.z); t[3] = f2bf(a.w);
            t[4] = f2bf(c.x); t[5] = f2bf(c.y); t[6] = f2bf(c.z); t[7] = f2bf(c.w);
            qf[dk] = t;
        }
    }

    f32x4 acc[8];
    #pragma unroll
    for (int i = 0; i < 8; ++i) acc[i] = (f32x4){0.f, 0.f, 0.f, 0.f};
    float m_r[4] = {-INFINITY, -INFINITY, -INFINITY, -INFINITY};
    float l_r[4] = {0.f, 0.f, 0.f, 0.f};

    for (int kt = 0; kt <= qt; ++kt) {
        const int kvbase = kt * KVBLK;
        __syncthreads();   // prior tile fully consumed before restage

        // ---- stage K tile [64][128] fp32 -> bf16 LDS, coalesced ----
        {
            const float4* kg4 = (const float4*)(Kg + base + (size_t)kvbase * D_HEAD);
            #pragma unroll
            for (int u = 0; u < 8; ++u) {
                int id  = tid + 256 * u;     // 2048 float4
                int row = id >> 5;
                int c4  = id & 31;
                float4 v4 = kg4[id];
                s16x4 s4;
                s4[0] = f2bf(v4.x); s4[1] = f2bf(v4.y);
                s4[2] = f2bf(v4.z); s4[3] = f2bf(v4.w);
                *(s16x4*)&Klds[row][c4 * 4] = s4;
            }
        }
        // ---- stage V tile transposed: Vt[d][key], coalesced loads ----
        {
            const float* vg = Vg + base + (size_t)kvbase * D_HEAD;
            #pragma unroll
            for (int u = 0; u < 16; ++u) {
                int id = tid + 256 * u;      // 4096 units: (kp 0..31) x (d 0..127)
                int d  = id & 127;
                int kp = id >> 7;
                float v0 = vg[(size_t)(2 * kp) * D_HEAD + d];
                float v1 = vg[(size_t)(2 * kp + 1) * D_HEAD + d];
                s16x2 s2; s2[0] = f2bf(v0); s2[1] = f2bf(v1);
                *(s16x2*)&Vlds[d][2 * kp] = s2;
            }
        }
        __syncthreads();

        // ---- QK^T: S[16x64] = Q[16x128] * K^T ----
        f32x4 sc[4];
        #pragma unroll
        for (int cf = 0; cf < 4; ++cf) sc[cf] = (f32x4){0.f, 0.f, 0.f, 0.f};
        #pragma unroll
        for (int cf = 0; cf < 4; ++cf) {
            #pragma unroll
            for (int dk = 0; dk < 4; ++dk) {
                bf16x8 kf = *(bf16x8*)&Klds[cf * 16 + l16][dk * 32 + lhi * 8];
                sc[cf] = __builtin_amdgcn_mfma_f32_16x16x32_bf16(
                    __builtin_bit_cast(bf16x8, qf[dk]), kf, sc[cf], 0, 0, 0);
            }
        }

        // ---- masks + scale; C layout: col=key=cf*16+l16, row=lhi*4+r ----
        float mkf[4];
        #pragma unroll
        for (int cf = 0; cf < 4; ++cf)
            mkf[cf] = (float)Mg[bidx * T_SEQ + kvbase + cf * 16 + l16];

        float p[4][4];
        const bool diag = (kt == qt);
        #pragma unroll
        for (int cf = 0; cf < 4; ++cf) {
            int key = kvbase + cf * 16 + l16;
            #pragma unroll
            for (int r = 0; r < 4; ++r) {
                float s = sc[cf][r] * SCALE + mkf[cf] * MASK_NUM;
                int qrow = qrow0 + lhi * 4 + r;
                if (diag && key > qrow) s = MASK_NUM;
                p[cf][r] = s;
            }
        }

        // ---- online softmax (per lane-row, reduce across 16-lane group) ----
        #pragma unroll
        for (int r = 0; r < 4; ++r) {
            float mx = fmaxf(fmaxf(p[0][r], p[1][r]), fmaxf(p[2][r], p[3][r]));
            #pragma unroll
            for (int off = 1; off < 16; off <<= 1)
                mx = fmaxf(mx, __shfl_xor(mx, off));
            float mnew  = fmaxf(m_r[r], mx);
            float alpha = __expf(m_r[r] - mnew);   // exp(-inf)=0 first time
            m_r[r] = mnew;
            float rs = 0.f;
            #pragma unroll
            for (int cf = 0; cf < 4; ++cf) {
                float pv = __expf(p[cf][r] - mnew);
                p[cf][r] = pv;
                rs += pv;
            }
            #pragma unroll
            for (int off = 1; off < 16; off <<= 1)
                rs += __shfl_xor(rs, off);
            l_r[r] = l_r[r] * alpha + rs;
            #pragma unroll
            for (int cfo = 0; cfo < 8; ++cfo) acc[cfo][r] *= alpha;
        }

        // ---- P: C-layout -> A-layout via per-wave LDS (no barrier needed) ----
        #pragma unroll
        for (int cf = 0; cf < 4; ++cf) {
            #pragma unroll
            for (int r = 0; r < 4; ++r)
                Plds[w][lhi * 4 + r][cf * 16 + l16] = f2bf(p[cf][r]);
        }
        bf16x8 pf0 = *(bf16x8*)&Plds[w][l16][lhi * 8];
        bf16x8 pf1 = *(bf16x8*)&Plds[w][l16][32 + lhi * 8];

        // ---- PV: O[16x128] += P[16x64] * V[64x128] ----
        #pragma unroll
        for (int cfo = 0; cfo < 8; ++cfo) {
            bf16x8 vf0 = *(bf16x8*)&Vlds[cfo * 16 + l16][lhi * 8];
            bf16x8 vf1 = *(bf16x8*)&Vlds[cfo * 16 + l16][32 + lhi * 8];
            acc[cfo] = __builtin_amdgcn_mfma_f32_16x16x32_bf16(pf0, vf0, acc[cfo], 0, 0, 0);
            acc[cfo] = __builtin_amdgcn_mfma_f32_16x16x32_bf16(pf1, vf1, acc[cfo], 0, 0, 0);
        }
    }

    // ---- degenerate rows (entire causal prefix key-masked): reference gives
    // uniform weight to ALL 1024 keys. Detect block-wide, then sweep the
    // future tiles with p = exp(MASK_NUM - m): 1 for degenerate rows, 0 else.
    {
        bool deg = (m_r[0] < -1e9f) | (m_r[1] < -1e9f) |
                   (m_r[2] < -1e9f) | (m_r[3] < -1e9f);
        __syncthreads();
        if (deg) degAny = 1;
        __syncthreads();
        if (degAny) {
            for (int kt = qt + 1; kt < T_SEQ / KVBLK; ++kt) {
                const int kvbase = kt * KVBLK;
                __syncthreads();
                const float* vg = Vg + base + (size_t)kvbase * D_HEAD;
                #pragma unroll
                for (int u = 0; u < 16; ++u) {
                    int id = tid + 256 * u;
                    int d  = id & 127;
                    int kp = id >> 7;
                    float v0 = vg[(size_t)(2 * kp) * D_HEAD + d];
                    float v1 = vg[(size_t)(2 * kp + 1) * D_HEAD + d];
                    s16x2 s2; s2[0] = f2bf(v0); s2[1] = f2bf(v1);
                    *(s16x2*)&Vlds[d][2 * kp] = s2;
                }
                __syncthreads();
                float pv_r[4];
                #pragma unroll
                for (int r = 0; r < 4; ++r) {
                    float pv = __expf(MASK_NUM - m_r[r]);  // 1 if degenerate, 0 else
                    pv_r[r] = pv;
                    l_r[r] += 64.0f * pv;                  // m, alpha unchanged
                }
                #pragma unroll
                for (int cf = 0; cf < 4; ++cf)
                    #pragma unroll
                    for (int r = 0; r < 4; ++r)
                        Plds[w][lhi * 4 + r][cf * 16 + l16] = f2bf(pv_r[r]);
                bf16x8 pf0 = *(bf16x8*)&Plds[w][l16][lhi * 8];
                bf16x8 pf1 = *(bf16x8*)&Plds[w][l16][32 + lhi * 8];
                #pragma unroll
                for (int cfo = 0; cfo < 8; ++cfo) {
                    bf16x8 vf0 = *(bf16x8*)&Vlds[cfo * 16 + l16][lhi * 8];
                    bf16x8 vf1 = *(bf16x8*)&Vlds[cfo * 16 + l16][32 + lhi * 8];
                    acc[cfo] = __builtin_amdgcn_mfma_f32_16x16x32_bf16(pf0, vf0, acc[cfo], 0, 0, 0);
                    acc[cfo] = __builtin_amdgcn_mfma_f32_16x16x32_bf16(pf1, vf1, acc[cfo], 0, 0, 0);
                }
            }
        }
    }

    // ---- epilogue: O = acc / l ----
    float inv[4];
    #pragma unroll
    for (int r = 0; r < 4; ++r) inv[r] = 1.0f / l_r[r];  // l >= 1 always
    float* op = Og + base;
    #pragma unroll
    for (int cfo = 0; cfo < 8; ++cfo) {
        #pragma unroll
        for (int r = 0; r < 4; ++r) {
            int qrow = qrow0 + lhi * 4 + r;
            op[(size_t)qrow * D_HEAD + cfo * 16 + l16] = acc[cfo][r] * inv[r];
        }
    }
}

extern "C" void kernel_launch(void* const* d_in, const int* in_sizes, int n_in,
                              void* d_out, int out_size, void* d_ws, size_t ws_size,
                              hipStream_t stream) {
    const float* Q = (const float*)d_in[0];
    const float* K = (const float*)d_in[1];
    const float* V = (const float*)d_in[2];
    const int*   M = (const int*)d_in[3];
    float*       O = (float*)d_out;
    dim3 grid(T_SEQ / QBLK, 256);   // x = q-tile (same-bh blocks adjacent), y = bh
    fa_kernel<<<grid, dim3(256), 0, stream>>>(Q, K, V, M, O);
}

// Round 4
// 762.560 us; speedup vs baseline: 2.0065x; 2.0065x over previous
//
#include <hip/hip_runtime.h>
#include <hip/hip_bf16.h>

// Flash attention fwd, causal + key-padding mask, bf16 MFMA, fp32 softmax.
// BH=256, T=1024, D=128, B=32 (mask row = bh % 32). MASK_NUM kept finite so
// degenerate all-masked rows reproduce the reference's uniform softmax over
// ALL 1024 keys (future tiles swept V-only at the end).
//
// Round-4 structure: 8-wave blocks (QBLK=128 q-rows), KVBLK=64, single-buffer
// LDS with REGISTER prefetch of tile kt+1 issued before compute of tile kt
// (T14 async-stage: HBM latency hides under QK^T+softmax+PV).

typedef __attribute__((ext_vector_type(8))) __bf16 bf16x8;
typedef __attribute__((ext_vector_type(8))) short s16x8;
typedef __attribute__((ext_vector_type(4))) short s16x4;
typedef __attribute__((ext_vector_type(4))) float f32x4;

#define T_SEQ    1024
#define D_HEAD   128
#define N_BATCH  32
#define QBLK     128
#define KVBLK    64
#define NWAVES   8
#define NTHR     512
#define NKT      (T_SEQ / KVBLK)   // 16
#define KPAD     136
#define VPAD     72
#define PPAD     72
#define MASK_NUM (-4294967295.0f)  // -2^32+1 (rounds to -2^32 in fp32, as in jax)
#define SCALE    0.08838834764831845f

__device__ __forceinline__ short f2bf(float f) {
    union { float f; unsigned u; } v; v.f = f;
    unsigned r = v.u + 0x7fffu + ((v.u >> 16) & 1u);   // RNE
    return (short)(r >> 16);
}

__global__ __launch_bounds__(NTHR) void fa_kernel(
    const float* __restrict__ Qg, const float* __restrict__ Kg,
    const float* __restrict__ Vg, const int* __restrict__ Mg,
    float* __restrict__ Og)
{
    __shared__ short Klds[KVBLK][KPAD];        // [key][d]
    __shared__ short Vlds[D_HEAD][VPAD];       // transposed: [d][key]
    __shared__ short Plds[NWAVES][16][PPAD];   // per-wave P re-layout
    __shared__ int   degAny;

    const int bh  = blockIdx.x;                // 0..255
    const int qs  = blockIdx.y;                // q super-tile 0..7 (128 rows)
    const int tid = threadIdx.x;
    const int w    = tid >> 6;                 // wave 0..7
    const int lane = tid & 63;
    const int l16  = lane & 15;
    const int lhi  = lane >> 4;                // 0..3

    const int    bidx   = bh & (N_BATCH - 1);
    const size_t base   = (size_t)bh * T_SEQ * D_HEAD;
    const int    qrow0  = qs * QBLK + w * 16;  // wave's first q row
    const int    kt_max = 2 * qs + 1;

    if (tid == 0) degAny = 0;

    // ---- Q fragments: A-layout, row=l16, k(d)=dk*32+lhi*8+j ----
    s16x8 qf[4];
    {
        const float* qp = Qg + base + (size_t)(qrow0 + l16) * D_HEAD + lhi * 8;
        #pragma unroll
        for (int dk = 0; dk < 4; ++dk) {
            float4 a = *(const float4*)(qp + dk * 32);
            float4 c = *(const float4*)(qp + dk * 32 + 4);
            s16x8 t;
            t[0] = f2bf(a.x); t[1] = f2bf(a.y); t[2] = f2bf(a.z); t[3] = f2bf(a.w);
            t[4] = f2bf(c.x); t[5] = f2bf(c.y); t[6] = f2bf(c.z); t[7] = f2bf(c.w);
            qf[dk] = t;
        }
    }

    f32x4 acc[8];
    #pragma unroll
    for (int i = 0; i < 8; ++i) acc[i] = (f32x4){0.f, 0.f, 0.f, 0.f};
    float m_r[4] = {-INFINITY, -INFINITY, -INFINITY, -INFINITY};
    float l_r[4] = {0.f, 0.f, 0.f, 0.f};

    // ---- register prefetch of tile 0 (batched float4 issue) ----
    float4 kpre[4], vpre[4];
    {
        const float4* kg4 = (const float4*)(Kg + base);
        const float4* vg4 = (const float4*)(Vg + base);
        #pragma unroll
        for (int u = 0; u < 4; ++u) {
            int id = tid + NTHR * u;           // 2048 float4 per 64x128 tile
            kpre[u] = kg4[id];
            vpre[u] = vg4[id];
        }
    }

    for (int kt = 0; kt <= kt_max; ++kt) {
        const int kvbase = kt * KVBLK;

        // ---- convert prefetched regs -> LDS (vmcnt wait lands here) ----
        #pragma unroll
        for (int u = 0; u < 4; ++u) {
            int id  = tid + NTHR * u;
            int row = id >> 5;                 // 0..63
            int c4  = id & 31;                 // d-chunk
            s16x4 s4;
            s4[0] = f2bf(kpre[u].x); s4[1] = f2bf(kpre[u].y);
            s4[2] = f2bf(kpre[u].z); s4[3] = f2bf(kpre[u].w);
            *(s16x4*)&Klds[row][c4 * 4] = s4;
            Vlds[c4 * 4 + 0][row] = f2bf(vpre[u].x);
            Vlds[c4 * 4 + 1][row] = f2bf(vpre[u].y);
            Vlds[c4 * 4 + 2][row] = f2bf(vpre[u].z);
            Vlds[c4 * 4 + 3][row] = f2bf(vpre[u].w);
        }
        __syncthreads();   // stage visible

        // ---- issue NEXT tile's loads now; consumed after compute+barrier ----
        if (kt < kt_max) {
            const float4* kg4 = (const float4*)(Kg + base + (size_t)(kvbase + KVBLK) * D_HEAD);
            const float4* vg4 = (const float4*)(Vg + base + (size_t)(kvbase + KVBLK) * D_HEAD);
            #pragma unroll
            for (int u = 0; u < 4; ++u) {
                int id = tid + NTHR * u;
                kpre[u] = kg4[id];
                vpre[u] = vg4[id];
            }
        }

        // ---- QK^T: S[16x64] ----
        f32x4 sc[4];
        #pragma unroll
        for (int cf = 0; cf < 4; ++cf) sc[cf] = (f32x4){0.f, 0.f, 0.f, 0.f};
        #pragma unroll
        for (int cf = 0; cf < 4; ++cf) {
            #pragma unroll
            for (int dk = 0; dk < 4; ++dk) {
                bf16x8 kf = *(bf16x8*)&Klds[cf * 16 + l16][dk * 32 + lhi * 8];
                sc[cf] = __builtin_amdgcn_mfma_f32_16x16x32_bf16(
                    __builtin_bit_cast(bf16x8, qf[dk]), kf, sc[cf], 0, 0, 0);
            }
        }

        // ---- mask + scale; C layout: col=key=cf*16+l16, row=lhi*4+r ----
        float p[4][4];
        const bool anymask = (kvbase + KVBLK - 1 > qrow0);
        #pragma unroll
        for (int cf = 0; cf < 4; ++cf) {
            float mk = (float)Mg[bidx * T_SEQ + kvbase + cf * 16 + l16];
            int key = kvbase + cf * 16 + l16;
            #pragma unroll
            for (int r = 0; r < 4; ++r) {
                float s = sc[cf][r] * SCALE + mk * MASK_NUM;
                int qrow = qrow0 + lhi * 4 + r;
                if (anymask && key > qrow) s = MASK_NUM;
                p[cf][r] = s;
            }
        }

        // ---- online softmax (16-lane-group reduce) ----
        #pragma unroll
        for (int r = 0; r < 4; ++r) {
            float mx = fmaxf(fmaxf(p[0][r], p[1][r]), fmaxf(p[2][r], p[3][r]));
            #pragma unroll
            for (int off = 1; off < 16; off <<= 1)
                mx = fmaxf(mx, __shfl_xor(mx, off));
            float mnew  = fmaxf(m_r[r], mx);
            float alpha = __expf(m_r[r] - mnew);
            m_r[r] = mnew;
            float rs = 0.f;
            #pragma unroll
            for (int cf = 0; cf < 4; ++cf) {
                float pv = __expf(p[cf][r] - mnew);
                p[cf][r] = pv;
                rs += pv;
            }
            #pragma unroll
            for (int off = 1; off < 16; off <<= 1)
                rs += __shfl_xor(rs, off);
            l_r[r] = l_r[r] * alpha + rs;
            #pragma unroll
            for (int cfo = 0; cfo < 8; ++cfo) acc[cfo][r] *= alpha;
        }

        // ---- P: C-layout -> A-layout via per-wave LDS ----
        #pragma unroll
        for (int cf = 0; cf < 4; ++cf)
            #pragma unroll
            for (int r = 0; r < 4; ++r)
                Plds[w][lhi * 4 + r][cf * 16 + l16] = f2bf(p[cf][r]);
        bf16x8 pf0 = *(bf16x8*)&Plds[w][l16][lhi * 8];
        bf16x8 pf1 = *(bf16x8*)&Plds[w][l16][32 + lhi * 8];

        // ---- PV: O[16x128] += P[16x64] * V[64x128] ----
        #pragma unroll
        for (int cfo = 0; cfo < 8; ++cfo) {
            bf16x8 vf0 = *(bf16x8*)&Vlds[cfo * 16 + l16][lhi * 8];
            bf16x8 vf1 = *(bf16x8*)&Vlds[cfo * 16 + l16][32 + lhi * 8];
            acc[cfo] = __builtin_amdgcn_mfma_f32_16x16x32_bf16(pf0, vf0, acc[cfo], 0, 0, 0);
            acc[cfo] = __builtin_amdgcn_mfma_f32_16x16x32_bf16(pf1, vf1, acc[cfo], 0, 0, 0);
        }
        __syncthreads();   // all reads done before next stage overwrites
    }

    // ---- degenerate rows: whole causal prefix masked => reference weights
    // ALL 1024 keys uniformly. Sweep future tiles V-only with
    // p = exp(MASK_NUM - m): 1 for degenerate rows, 0 (underflow) otherwise.
    {
        bool deg = (m_r[0] < -1e9f) | (m_r[1] < -1e9f) |
                   (m_r[2] < -1e9f) | (m_r[3] < -1e9f);
        __syncthreads();
        if (deg) degAny = 1;
        __syncthreads();
        if (degAny) {
            for (int kt = kt_max + 1; kt < NKT; ++kt) {
                const float4* vg4 = (const float4*)(Vg + base + (size_t)(kt * KVBLK) * D_HEAD);
                #pragma unroll
                for (int u = 0; u < 4; ++u) {
                    int id  = tid + NTHR * u;
                    int row = id >> 5;
                    int c4  = id & 31;
                    float4 v4 = vg4[id];
                    Vlds[c4 * 4 + 0][row] = f2bf(v4.x);
                    Vlds[c4 * 4 + 1][row] = f2bf(v4.y);
                    Vlds[c4 * 4 + 2][row] = f2bf(v4.z);
                    Vlds[c4 * 4 + 3][row] = f2bf(v4.w);
                }
                __syncthreads();
                float pv_r[4];
                #pragma unroll
                for (int r = 0; r < 4; ++r) {
                    float pv = __expf(MASK_NUM - m_r[r]);   // 1 if degenerate else 0
                    pv_r[r] = pv;
                    l_r[r] += 64.0f * pv;
                }
                #pragma unroll
                for (int cf = 0; cf < 4; ++cf)
                    #pragma unroll
                    for (int r = 0; r < 4; ++r)
                        Plds[w][lhi * 4 + r][cf * 16 + l16] = f2bf(pv_r[r]);
                bf16x8 pf0 = *(bf16x8*)&Plds[w][l16][lhi * 8];
                bf16x8 pf1 = *(bf16x8*)&Plds[w][l16][32 + lhi * 8];
                #pragma unroll
                for (int cfo = 0; cfo < 8; ++cfo) {
                    bf16x8 vf0 = *(bf16x8*)&Vlds[cfo * 16 + l16][lhi * 8];
                    bf16x8 vf1 = *(bf16x8*)&Vlds[cfo * 16 + l16][32 + lhi * 8];
                    acc[cfo] = __builtin_amdgcn_mfma_f32_16x16x32_bf16(pf0, vf0, acc[cfo], 0, 0, 0);
                    acc[cfo] = __builtin_amdgcn_mfma_f32_16x16x32_bf16(pf1, vf1, acc[cfo], 0, 0, 0);
                }
                __syncthreads();
            }
        }
    }

    // ---- epilogue: O = acc / l ----
    float inv[4];
    #pragma unroll
    for (int r = 0; r < 4; ++r) inv[r] = 1.0f / l_r[r];
    float* op = Og + base;
    #pragma unroll
    for (int cfo = 0; cfo < 8; ++cfo)
        #pragma unroll
        for (int r = 0; r < 4; ++r) {
            int qrow = qrow0 + lhi * 4 + r;
            op[(size_t)qrow * D_HEAD + cfo * 16 + l16] = acc[cfo][r] * inv[r];
        }
}

extern "C" void kernel_launch(void* const* d_in, const int* in_sizes, int n_in,
                              void* d_out, int out_size, void* d_ws, size_t ws_size,
                              hipStream_t stream) {
    const float* Q = (const float*)d_in[0];
    const float* K = (const float*)d_in[1];
    const float* V = (const float*)d_in[2];
    const int*   M = (const int*)d_in[3];
    float*       O = (float*)d_out;
    dim3 grid(256, T_SEQ / QBLK);   // x = bh (XCD spread), y = q super-tile
    fa_kernel<<<grid, dim3(NTHR), 0, stream>>>(Q, K, V, M, O);
}

// Round 7
// 720.375 us; speedup vs baseline: 2.1240x; 1.0586x over previous
//
#include <hip/hip_runtime.h>
#include <hip/hip_bf16.h>

// Flash attention fwd, causal + key-padding mask, bf16 MFMA, fp32 softmax.
// BH=256, T=1024, D=128, B=32 (mask row = bh % 32). MASK_NUM kept finite so
// degenerate all-masked rows reproduce the reference's uniform softmax over
// ALL 1024 keys (future tiles swept V-only at the end).
//
// Round-5 (3rd submit, unchanged): (a) V staged with lane-consecutive d +
// packed key-pair b32 writes (8 lanes/bank instead of 32); (b) heavy-first
// balanced dispatch (qs = 7 - blockIdx.x); (c) setprio around MFMA clusters.

typedef __attribute__((ext_vector_type(8))) __bf16 bf16x8;
typedef __attribute__((ext_vector_type(8))) short s16x8;
typedef __attribute__((ext_vector_type(4))) short s16x4;
typedef __attribute__((ext_vector_type(2))) short s16x2;
typedef __attribute__((ext_vector_type(4))) float f32x4;

#define T_SEQ    1024
#define D_HEAD   128
#define N_BATCH  32
#define QBLK     128
#define KVBLK    64
#define NWAVES   8
#define NTHR     512
#define NKT      (T_SEQ / KVBLK)   // 16
#define KPAD     136
#define VPAD     72
#define PPAD     72
#define MASK_NUM (-4294967295.0f)  // -2^32+1 (rounds to -2^32 in fp32, as in jax)
#define SCALE    0.08838834764831845f

__device__ __forceinline__ short f2bf(float f) {
    union { float f; unsigned u; } v; v.f = f;
    unsigned r = v.u + 0x7fffu + ((v.u >> 16) & 1u);   // RNE
    return (short)(r >> 16);
}

__global__ __launch_bounds__(NTHR) void fa_kernel(
    const float* __restrict__ Qg, const float* __restrict__ Kg,
    const float* __restrict__ Vg, const int* __restrict__ Mg,
    float* __restrict__ Og)
{
    __shared__ short Klds[KVBLK][KPAD];        // [key][d]
    __shared__ short Vlds[D_HEAD][VPAD];       // transposed: [d][key]
    __shared__ short Plds[NWAVES][16][PPAD];   // per-wave P re-layout
    __shared__ int   degAny;

    const int qs  = 7 - blockIdx.x;            // heavy q super-tiles first
    const int bh  = blockIdx.y;                // 0..255
    const int tid = threadIdx.x;
    const int w    = tid >> 6;                 // wave 0..7
    const int lane = tid & 63;
    const int l16  = lane & 15;
    const int lhi  = lane >> 4;                // 0..3

    const int    bidx   = bh & (N_BATCH - 1);
    const size_t base   = (size_t)bh * T_SEQ * D_HEAD;
    const int    qrow0  = qs * QBLK + w * 16;  // wave's first q row
    const int    kt_max = 2 * qs + 1;

    // V staging geometry: d = tid&127 (lane-consecutive), key-pair kp.
    const int vd  = tid & 127;
    const int vkp = tid >> 7;                  // 0..3 base; +4 per u

    if (tid == 0) degAny = 0;

    // ---- Q fragments: A-layout, row=l16, k(d)=dk*32+lhi*8+j ----
    s16x8 qf[4];
    {
        const float* qp = Qg + base + (size_t)(qrow0 + l16) * D_HEAD + lhi * 8;
        #pragma unroll
        for (int dk = 0; dk < 4; ++dk) {
            float4 a = *(const float4*)(qp + dk * 32);
            float4 c = *(const float4*)(qp + dk * 32 + 4);
            s16x8 t;
            t[0] = f2bf(a.x); t[1] = f2bf(a.y); t[2] = f2bf(a.z); t[3] = f2bf(a.w);
            t[4] = f2bf(c.x); t[5] = f2bf(c.y); t[6] = f2bf(c.z); t[7] = f2bf(c.w);
            qf[dk] = t;
        }
    }

    f32x4 acc[8];
    #pragma unroll
    for (int i = 0; i < 8; ++i) acc[i] = (f32x4){0.f, 0.f, 0.f, 0.f};
    float m_r[4] = {-INFINITY, -INFINITY, -INFINITY, -INFINITY};
    float l_r[4] = {0.f, 0.f, 0.f, 0.f};

    // ---- register prefetch of tile 0 ----
    float4 kpre[4];
    float  vpre0[8], vpre1[8];
    {
        const float4* kg4 = (const float4*)(Kg + base);
        const float*  vg  = Vg + base;
        #pragma unroll
        for (int u = 0; u < 4; ++u)
            kpre[u] = kg4[tid + NTHR * u];
        #pragma unroll
        for (int u = 0; u < 8; ++u) {
            int kp = vkp + 4 * u;
            vpre0[u] = vg[(size_t)(2 * kp) * D_HEAD + vd];
            vpre1[u] = vg[(size_t)(2 * kp + 1) * D_HEAD + vd];
        }
    }

    for (int kt = 0; kt <= kt_max; ++kt) {
        const int kvbase = kt * KVBLK;

        // ---- convert prefetched regs -> LDS ----
        #pragma unroll
        for (int u = 0; u < 4; ++u) {
            int id  = tid + NTHR * u;
            int row = id >> 5;
            int c4  = id & 31;
            s16x4 s4;
            s4[0] = f2bf(kpre[u].x); s4[1] = f2bf(kpre[u].y);
            s4[2] = f2bf(kpre[u].z); s4[3] = f2bf(kpre[u].w);
            *(s16x4*)&Klds[row][c4 * 4] = s4;
        }
        #pragma unroll
        for (int u = 0; u < 8; ++u) {
            int kp = vkp + 4 * u;
            s16x2 s2; s2[0] = f2bf(vpre0[u]); s2[1] = f2bf(vpre1[u]);
            *(s16x2*)&Vlds[vd][2 * kp] = s2;
        }
        __syncthreads();   // stage visible

        // ---- issue NEXT tile's loads; consumed after compute+barrier ----
        if (kt < kt_max) {
            const float4* kg4 = (const float4*)(Kg + base + (size_t)(kvbase + KVBLK) * D_HEAD);
            const float*  vg  = Vg + base + (size_t)(kvbase + KVBLK) * D_HEAD;
            #pragma unroll
            for (int u = 0; u < 4; ++u)
                kpre[u] = kg4[tid + NTHR * u];
            #pragma unroll
            for (int u = 0; u < 8; ++u) {
                int kp = vkp + 4 * u;
                vpre0[u] = vg[(size_t)(2 * kp) * D_HEAD + vd];
                vpre1[u] = vg[(size_t)(2 * kp + 1) * D_HEAD + vd];
            }
        }

        // ---- QK^T: S[16x64] ----
        f32x4 sc[4];
        #pragma unroll
        for (int cf = 0; cf < 4; ++cf) sc[cf] = (f32x4){0.f, 0.f, 0.f, 0.f};
        __builtin_amdgcn_s_setprio(1);
        #pragma unroll
        for (int cf = 0; cf < 4; ++cf) {
            #pragma unroll
            for (int dk = 0; dk < 4; ++dk) {
                bf16x8 kf = *(bf16x8*)&Klds[cf * 16 + l16][dk * 32 + lhi * 8];
                sc[cf] = __builtin_amdgcn_mfma_f32_16x16x32_bf16(
                    __builtin_bit_cast(bf16x8, qf[dk]), kf, sc[cf], 0, 0, 0);
            }
        }
        __builtin_amdgcn_s_setprio(0);

        // ---- mask + scale; C layout: col=key=cf*16+l16, row=lhi*4+r ----
        float p[4][4];
        const bool anymask = (kvbase + KVBLK - 1 > qrow0);
        #pragma unroll
        for (int cf = 0; cf < 4; ++cf) {
            float mk = (float)Mg[bidx * T_SEQ + kvbase + cf * 16 + l16];
            int key = kvbase + cf * 16 + l16;
            #pragma unroll
            for (int r = 0; r < 4; ++r) {
                float s = sc[cf][r] * SCALE + mk * MASK_NUM;
                int qrow = qrow0 + lhi * 4 + r;
                if (anymask && key > qrow) s = MASK_NUM;
                p[cf][r] = s;
            }
        }

        // ---- online softmax (16-lane-group reduce) ----
        #pragma unroll
        for (int r = 0; r < 4; ++r) {
            float mx = fmaxf(fmaxf(p[0][r], p[1][r]), fmaxf(p[2][r], p[3][r]));
            #pragma unroll
            for (int off = 1; off < 16; off <<= 1)
                mx = fmaxf(mx, __shfl_xor(mx, off));
            float mnew  = fmaxf(m_r[r], mx);
            float alpha = __expf(m_r[r] - mnew);
            m_r[r] = mnew;
            float rs = 0.f;
            #pragma unroll
            for (int cf = 0; cf < 4; ++cf) {
                float pv = __expf(p[cf][r] - mnew);
                p[cf][r] = pv;
                rs += pv;
            }
            #pragma unroll
            for (int off = 1; off < 16; off <<= 1)
                rs += __shfl_xor(rs, off);
            l_r[r] = l_r[r] * alpha + rs;
            #pragma unroll
            for (int cfo = 0; cfo < 8; ++cfo) acc[cfo][r] *= alpha;
        }

        // ---- P: C-layout -> A-layout via per-wave LDS ----
        #pragma unroll
        for (int cf = 0; cf < 4; ++cf)
            #pragma unroll
            for (int r = 0; r < 4; ++r)
                Plds[w][lhi * 4 + r][cf * 16 + l16] = f2bf(p[cf][r]);
        bf16x8 pf0 = *(bf16x8*)&Plds[w][l16][lhi * 8];
        bf16x8 pf1 = *(bf16x8*)&Plds[w][l16][32 + lhi * 8];

        // ---- PV: O[16x128] += P[16x64] * V[64x128] ----
        __builtin_amdgcn_s_setprio(1);
        #pragma unroll
        for (int cfo = 0; cfo < 8; ++cfo) {
            bf16x8 vf0 = *(bf16x8*)&Vlds[cfo * 16 + l16][lhi * 8];
            bf16x8 vf1 = *(bf16x8*)&Vlds[cfo * 16 + l16][32 + lhi * 8];
            acc[cfo] = __builtin_amdgcn_mfma_f32_16x16x32_bf16(pf0, vf0, acc[cfo], 0, 0, 0);
            acc[cfo] = __builtin_amdgcn_mfma_f32_16x16x32_bf16(pf1, vf1, acc[cfo], 0, 0, 0);
        }
        __builtin_amdgcn_s_setprio(0);
        __syncthreads();   // all reads done before next stage overwrites
    }

    // ---- degenerate rows: whole causal prefix masked => reference weights
    // ALL 1024 keys uniformly. Sweep future tiles V-only with
    // p = exp(MASK_NUM - m): 1 for degenerate rows, 0 (underflow) otherwise.
    {
        bool deg = (m_r[0] < -1e9f) | (m_r[1] < -1e9f) |
                   (m_r[2] < -1e9f) | (m_r[3] < -1e9f);
        __syncthreads();
        if (deg) degAny = 1;
        __syncthreads();
        if (degAny) {
            for (int kt = kt_max + 1; kt < NKT; ++kt) {
                const float* vg = Vg + base + (size_t)(kt * KVBLK) * D_HEAD;
                #pragma unroll
                for (int u = 0; u < 8; ++u) {
                    int kp = vkp + 4 * u;
                    float v0 = vg[(size_t)(2 * kp) * D_HEAD + vd];
                    float v1 = vg[(size_t)(2 * kp + 1) * D_HEAD + vd];
                    s16x2 s2; s2[0] = f2bf(v0); s2[1] = f2bf(v1);
                    *(s16x2*)&Vlds[vd][2 * kp] = s2;
                }
                __syncthreads();
                float pv_r[4];
                #pragma unroll
                for (int r = 0; r < 4; ++r) {
                    float pv = __expf(MASK_NUM - m_r[r]);   // 1 if degenerate else 0
                    pv_r[r] = pv;
                    l_r[r] += 64.0f * pv;
                }
                #pragma unroll
                for (int cf = 0; cf < 4; ++cf)
                    #pragma unroll
                    for (int r = 0; r < 4; ++r)
                        Plds[w][lhi * 4 + r][cf * 16 + l16] = f2bf(pv_r[r]);
                bf16x8 pf0 = *(bf16x8*)&Plds[w][l16][lhi * 8];
                bf16x8 pf1 = *(bf16x8*)&Plds[w][l16][32 + lhi * 8];
                #pragma unroll
                for (int cfo = 0; cfo < 8; ++cfo) {
                    bf16x8 vf0 = *(bf16x8*)&Vlds[cfo * 16 + l16][lhi * 8];
                    bf16x8 vf1 = *(bf16x8*)&Vlds[cfo * 16 + l16][32 + lhi * 8];
                    acc[cfo] = __builtin_amdgcn_mfma_f32_16x16x32_bf16(pf0, vf0, acc[cfo], 0, 0, 0);
                    acc[cfo] = __builtin_amdgcn_mfma_f32_16x16x32_bf16(pf1, vf1, acc[cfo], 0, 0, 0);
                }
                __syncthreads();
            }
        }
    }

    // ---- epilogue: O = acc / l ----
    float inv[4];
    #pragma unroll
    for (int r = 0; r < 4; ++r) inv[r] = 1.0f / l_r[r];
    float* op = Og + base;
    #pragma unroll
    for (int cfo = 0; cfo < 8; ++cfo)
        #pragma unroll
        for (int r = 0; r < 4; ++r) {
            int qrow = qrow0 + lhi * 4 + r;
            op[(size_t)qrow * D_HEAD + cfo * 16 + l16] = acc[cfo][r] * inv[r];
        }
}

extern "C" void kernel_launch(void* const* d_in, const int* in_sizes, int n_in,
                              void* d_out, int out_size, void* d_ws, size_t ws_size,
                              hipStream_t stream) {
    const float* Q = (const float*)d_in[0];
    const float* K = (const float*)d_in[1];
    const float* V = (const float*)d_in[2];
    const int*   M = (const int*)d_in[3];
    float*       O = (float*)d_out;
    dim3 grid(T_SEQ / QBLK, 256);   // x = qs slot (heavy first), y = bh
    fa_kernel<<<grid, dim3(NTHR), 0, stream>>>(Q, K, V, M, O);
}

// Round 8
// 572.342 us; speedup vs baseline: 2.6733x; 1.2586x over previous
//
#include <hip/hip_runtime.h>
#include <hip/hip_bf16.h>

// Flash attention fwd, causal + key-padding mask, bf16 MFMA, fp32 softmax.
// BH=256, T=1024, D=128, B=32 (mask row = bh % 32). MASK_NUM kept finite so
// degenerate all-masked rows reproduce the reference's uniform softmax over
// ALL 1024 keys (future tiles swept V-only at the end).
//
// Round-8: (a) SWAPPED QK^T: sc = mfma(K, Q) puts q-row = lane&15, keys
// in-lane -> softmax is a register tree + 2 shfl_xor (was 32 chained shfl),
// P-relayout 4x b64 writes (was 16x b16), mask from LDS broadcast table;
// (b) XCD-balanced heavy-first grid: bh = blockIdx.x (XCD=bh%8), qs = 7-y.

typedef __attribute__((ext_vector_type(8))) __bf16 bf16x8;
typedef __attribute__((ext_vector_type(8))) short s16x8;
typedef __attribute__((ext_vector_type(4))) short s16x4;
typedef __attribute__((ext_vector_type(2))) short s16x2;
typedef __attribute__((ext_vector_type(4))) float f32x4;

#define T_SEQ    1024
#define D_HEAD   128
#define N_BATCH  32
#define QBLK     128
#define KVBLK    64
#define NWAVES   8
#define NTHR     512
#define NKT      (T_SEQ / KVBLK)   // 16
#define KPAD     136
#define VPAD     72
#define PPAD     72
#define MASK_NUM (-4294967295.0f)  // -2^32+1 -> rounds to -2^32 in fp32 (same as jax)
#define SCALE    0.08838834764831845f

__device__ __forceinline__ short f2bf(float f) {
    union { float f; unsigned u; } v; v.f = f;
    unsigned r = v.u + 0x7fffu + ((v.u >> 16) & 1u);   // RNE
    return (short)(r >> 16);
}

__global__ __launch_bounds__(NTHR) void fa_kernel(
    const float* __restrict__ Qg, const float* __restrict__ Kg,
    const float* __restrict__ Vg, const int* __restrict__ Mg,
    float* __restrict__ Og)
{
    __shared__ short Klds[KVBLK][KPAD];        // [key][d]
    __shared__ short Vlds[D_HEAD][VPAD];       // transposed: [d][key]
    __shared__ short Plds[NWAVES][16][PPAD];   // per-wave P re-layout [q][key]
    __shared__ float Mlds[T_SEQ];              // mask[key] * MASK_NUM (additive)
    __shared__ int   degAny;

    const int bh  = blockIdx.x;                // 0..255 -> XCD = bh%8 (balanced)
    const int qs  = 7 - blockIdx.y;            // heavy q super-tiles dispatch first
    const int tid = threadIdx.x;
    const int w    = tid >> 6;                 // wave 0..7
    const int lane = tid & 63;
    const int l16  = lane & 15;
    const int lhi  = lane >> 4;                // 0..3

    const int    bidx   = bh & (N_BATCH - 1);
    const size_t base   = (size_t)bh * T_SEQ * D_HEAD;
    const int    qrow0  = qs * QBLK + w * 16;  // wave's first q row
    const int    qrow   = qrow0 + l16;         // THIS lane's q row (softmax row)
    const int    kt_max = 2 * qs + 1;

    // V staging geometry: d = tid&127 (lane-consecutive), key-pair kp.
    const int vd  = tid & 127;
    const int vkp = tid >> 7;                  // 0..3 base; +4 per u

    if (tid == 0) degAny = 0;
    // ---- mask table: additive float per key (visible after first barrier) ----
    Mlds[tid]        = (float)Mg[bidx * T_SEQ + tid] * MASK_NUM;
    Mlds[tid + NTHR] = (float)Mg[bidx * T_SEQ + tid + NTHR] * MASK_NUM;

    // ---- Q fragments (B-operand): row=l16=q, k(d)=dk*32+lhi*8+j ----
    s16x8 qf[4];
    {
        const float* qp = Qg + base + (size_t)qrow * D_HEAD + lhi * 8;
        #pragma unroll
        for (int dk = 0; dk < 4; ++dk) {
            float4 a = *(const float4*)(qp + dk * 32);
            float4 c = *(const float4*)(qp + dk * 32 + 4);
            s16x8 t;
            t[0] = f2bf(a.x); t[1] = f2bf(a.y); t[2] = f2bf(a.z); t[3] = f2bf(a.w);
            t[4] = f2bf(c.x); t[5] = f2bf(c.y); t[6] = f2bf(c.z); t[7] = f2bf(c.w);
            qf[dk] = t;
        }
    }

    f32x4 acc[8];                              // O: col=l16=d, row=lhi*4+r=q'
    #pragma unroll
    for (int i = 0; i < 8; ++i) acc[i] = (f32x4){0.f, 0.f, 0.f, 0.f};
    float m_run = -INFINITY, l_run = 0.f;      // per-lane: one q-row

    // ---- register prefetch of tile 0 ----
    float4 kpre[4];
    float  vpre0[8], vpre1[8];
    {
        const float4* kg4 = (const float4*)(Kg + base);
        const float*  vg  = Vg + base;
        #pragma unroll
        for (int u = 0; u < 4; ++u)
            kpre[u] = kg4[tid + NTHR * u];
        #pragma unroll
        for (int u = 0; u < 8; ++u) {
            int kp = vkp + 4 * u;
            vpre0[u] = vg[(size_t)(2 * kp) * D_HEAD + vd];
            vpre1[u] = vg[(size_t)(2 * kp + 1) * D_HEAD + vd];
        }
    }

    for (int kt = 0; kt <= kt_max; ++kt) {
        const int kvbase = kt * KVBLK;

        // ---- convert prefetched regs -> LDS ----
        #pragma unroll
        for (int u = 0; u < 4; ++u) {
            int id  = tid + NTHR * u;
            int row = id >> 5;
            int c4  = id & 31;
            s16x4 s4;
            s4[0] = f2bf(kpre[u].x); s4[1] = f2bf(kpre[u].y);
            s4[2] = f2bf(kpre[u].z); s4[3] = f2bf(kpre[u].w);
            *(s16x4*)&Klds[row][c4 * 4] = s4;
        }
        #pragma unroll
        for (int u = 0; u < 8; ++u) {
            int kp = vkp + 4 * u;
            s16x2 s2; s2[0] = f2bf(vpre0[u]); s2[1] = f2bf(vpre1[u]);
            *(s16x2*)&Vlds[vd][2 * kp] = s2;
        }
        __syncthreads();   // stage + mask table visible

        // ---- issue NEXT tile's loads; consumed after compute+barrier ----
        if (kt < kt_max) {
            const float4* kg4 = (const float4*)(Kg + base + (size_t)(kvbase + KVBLK) * D_HEAD);
            const float*  vg  = Vg + base + (size_t)(kvbase + KVBLK) * D_HEAD;
            #pragma unroll
            for (int u = 0; u < 4; ++u)
                kpre[u] = kg4[tid + NTHR * u];
            #pragma unroll
            for (int u = 0; u < 8; ++u) {
                int kp = vkp + 4 * u;
                vpre0[u] = vg[(size_t)(2 * kp) * D_HEAD + vd];
                vpre1[u] = vg[(size_t)(2 * kp + 1) * D_HEAD + vd];
            }
        }

        // ---- QK^T swapped: S^T[64k x 16q] = K * Q^T; col=l16=q, row=k ----
        f32x4 sc[4];
        #pragma unroll
        for (int cf = 0; cf < 4; ++cf) sc[cf] = (f32x4){0.f, 0.f, 0.f, 0.f};
        __builtin_amdgcn_s_setprio(1);
        #pragma unroll
        for (int cf = 0; cf < 4; ++cf) {
            #pragma unroll
            for (int dk = 0; dk < 4; ++dk) {
                bf16x8 kf = *(bf16x8*)&Klds[cf * 16 + l16][dk * 32 + lhi * 8];
                sc[cf] = __builtin_amdgcn_mfma_f32_16x16x32_bf16(
                    kf, __builtin_bit_cast(bf16x8, qf[dk]), sc[cf], 0, 0, 0);
            }
        }
        __builtin_amdgcn_s_setprio(0);

        // ---- mask + scale + causal; lane's key = kvbase + cf*16 + lhi*4 + r ----
        float p[4][4];
        const bool diag = (kvbase + KVBLK - 1 > qrow0);
        #pragma unroll
        for (int cf = 0; cf < 4; ++cf) {
            float4 mv = *(const float4*)&Mlds[kvbase + cf * 16 + lhi * 4];
            #pragma unroll
            for (int r = 0; r < 4; ++r) {
                float s = sc[cf][r] * SCALE + ((const float*)&mv)[r];
                int key = kvbase + cf * 16 + lhi * 4 + r;
                if (diag && key > qrow) s = MASK_NUM;
                p[cf][r] = s;
            }
        }

        // ---- online softmax: in-lane tree + 2 shuffles (4 lanes share a q-row) ----
        float mx01 = fmaxf(fmaxf(p[0][0], p[0][1]), fmaxf(p[0][2], p[0][3]));
        float mx1  = fmaxf(fmaxf(p[1][0], p[1][1]), fmaxf(p[1][2], p[1][3]));
        float mx2  = fmaxf(fmaxf(p[2][0], p[2][1]), fmaxf(p[2][2], p[2][3]));
        float mx3  = fmaxf(fmaxf(p[3][0], p[3][1]), fmaxf(p[3][2], p[3][3]));
        float mx   = fmaxf(fmaxf(mx01, mx1), fmaxf(mx2, mx3));
        mx = fmaxf(mx, __shfl_xor(mx, 16));
        mx = fmaxf(mx, __shfl_xor(mx, 32));
        float mnew  = fmaxf(m_run, mx);
        float alpha = __expf(m_run - mnew);    // exp(-inf)=0 first time
        m_run = mnew;
        float rs = 0.f;
        #pragma unroll
        for (int cf = 0; cf < 4; ++cf)
            #pragma unroll
            for (int r = 0; r < 4; ++r) {
                float pv = __expf(p[cf][r] - mnew);
                p[cf][r] = pv;
                rs += pv;
            }
        rs += __shfl_xor(rs, 16);
        rs += __shfl_xor(rs, 32);
        l_run = l_run * alpha + rs;

        // ---- rescale acc: alpha for q'=lhi*4+r lives in lane l16=q' ----
        float a0 = __shfl(alpha, lhi * 4 + 0);
        float a1 = __shfl(alpha, lhi * 4 + 1);
        float a2 = __shfl(alpha, lhi * 4 + 2);
        float a3 = __shfl(alpha, lhi * 4 + 3);
        #pragma unroll
        for (int cfo = 0; cfo < 8; ++cfo) {
            acc[cfo][0] *= a0; acc[cfo][1] *= a1;
            acc[cfo][2] *= a2; acc[cfo][3] *= a3;
        }

        // ---- P re-layout: 4x b64 writes (consecutive keys), 2x b128 reads ----
        #pragma unroll
        for (int cf = 0; cf < 4; ++cf) {
            s16x4 s4;
            s4[0] = f2bf(p[cf][0]); s4[1] = f2bf(p[cf][1]);
            s4[2] = f2bf(p[cf][2]); s4[3] = f2bf(p[cf][3]);
            *(s16x4*)&Plds[w][l16][cf * 16 + lhi * 4] = s4;
        }
        bf16x8 pf0 = *(bf16x8*)&Plds[w][l16][lhi * 8];
        bf16x8 pf1 = *(bf16x8*)&Plds[w][l16][32 + lhi * 8];

        // ---- PV: O[16q x 128d] += P[16q x 64k] * V[64k x 128d] ----
        __builtin_amdgcn_s_setprio(1);
        #pragma unroll
        for (int cfo = 0; cfo < 8; ++cfo) {
            bf16x8 vf0 = *(bf16x8*)&Vlds[cfo * 16 + l16][lhi * 8];
            bf16x8 vf1 = *(bf16x8*)&Vlds[cfo * 16 + l16][32 + lhi * 8];
            acc[cfo] = __builtin_amdgcn_mfma_f32_16x16x32_bf16(pf0, vf0, acc[cfo], 0, 0, 0);
            acc[cfo] = __builtin_amdgcn_mfma_f32_16x16x32_bf16(pf1, vf1, acc[cfo], 0, 0, 0);
        }
        __builtin_amdgcn_s_setprio(0);
        __syncthreads();   // all reads done before next stage overwrites
    }

    // ---- degenerate rows: whole causal prefix masked => reference weights
    // ALL 1024 keys uniformly. Sweep future tiles V-only with p = 1 for
    // degenerate rows (m still exactly -2^32), 0 otherwise.
    {
        const bool deg = (m_run < -1e9f);
        if (deg) degAny = 1;
        __syncthreads();
        if (degAny) {
            const float pv  = deg ? 1.0f : 0.0f;
            const short pb  = f2bf(pv);
            for (int kt = kt_max + 1; kt < NKT; ++kt) {
                const float* vg = Vg + base + (size_t)(kt * KVBLK) * D_HEAD;
                #pragma unroll
                for (int u = 0; u < 8; ++u) {
                    int kp = vkp + 4 * u;
                    float v0 = vg[(size_t)(2 * kp) * D_HEAD + vd];
                    float v1 = vg[(size_t)(2 * kp + 1) * D_HEAD + vd];
                    s16x2 s2; s2[0] = f2bf(v0); s2[1] = f2bf(v1);
                    *(s16x2*)&Vlds[vd][2 * kp] = s2;
                }
                __syncthreads();
                l_run += 64.0f * pv;
                s16x4 s4 = {pb, pb, pb, pb};
                #pragma unroll
                for (int cf = 0; cf < 4; ++cf)
                    *(s16x4*)&Plds[w][l16][cf * 16 + lhi * 4] = s4;
                bf16x8 pf0 = *(bf16x8*)&Plds[w][l16][lhi * 8];
                bf16x8 pf1 = *(bf16x8*)&Plds[w][l16][32 + lhi * 8];
                #pragma unroll
                for (int cfo = 0; cfo < 8; ++cfo) {
                    bf16x8 vf0 = *(bf16x8*)&Vlds[cfo * 16 + l16][lhi * 8];
                    bf16x8 vf1 = *(bf16x8*)&Vlds[cfo * 16 + l16][32 + lhi * 8];
                    acc[cfo] = __builtin_amdgcn_mfma_f32_16x16x32_bf16(pf0, vf0, acc[cfo], 0, 0, 0);
                    acc[cfo] = __builtin_amdgcn_mfma_f32_16x16x32_bf16(pf1, vf1, acc[cfo], 0, 0, 0);
                }
                __syncthreads();
            }
        }
    }

    // ---- epilogue: O = acc / l; 1/l for q'=lhi*4+r from lane l16=q' ----
    float invl = 1.0f / l_run;
    float i0 = __shfl(invl, lhi * 4 + 0);
    float i1 = __shfl(invl, lhi * 4 + 1);
    float i2 = __shfl(invl, lhi * 4 + 2);
    float i3 = __shfl(invl, lhi * 4 + 3);
    float* op = Og + base;
    #pragma unroll
    for (int cfo = 0; cfo < 8; ++cfo) {
        op[(size_t)(qrow0 + lhi * 4 + 0) * D_HEAD + cfo * 16 + l16] = acc[cfo][0] * i0;
        op[(size_t)(qrow0 + lhi * 4 + 1) * D_HEAD + cfo * 16 + l16] = acc[cfo][1] * i1;
        op[(size_t)(qrow0 + lhi * 4 + 2) * D_HEAD + cfo * 16 + l16] = acc[cfo][2] * i2;
        op[(size_t)(qrow0 + lhi * 4 + 3) * D_HEAD + cfo * 16 + l16] = acc[cfo][3] * i3;
    }
}

extern "C" void kernel_launch(void* const* d_in, const int* in_sizes, int n_in,
                              void* d_out, int out_size, void* d_ws, size_t ws_size,
                              hipStream_t stream) {
    const float* Q = (const float*)d_in[0];
    const float* K = (const float*)d_in[1];
    const float* V = (const float*)d_in[2];
    const int*   M = (const int*)d_in[3];
    float*       O = (float*)d_out;
    // x = bh (XCD = bh%8, balanced), y: qs = 7-y (heavy blocks dispatch first)
    dim3 grid(256, T_SEQ / QBLK);
    fa_kernel<<<grid, dim3(NTHR), 0, stream>>>(Q, K, V, M, O);
}